// Round 14
// baseline (985.741 us; speedup 1.0000x reference)
//
#include <hip/hip_runtime.h>
#include <hip/hip_bf16.h>
#include <cstdint>
#include <cstddef>

typedef __bf16 bf16_t;
typedef __bf16 bf16x8 __attribute__((ext_vector_type(8)));
typedef float f32x4 __attribute__((ext_vector_type(4)));

#define GLP(p)  (const __attribute__((address_space(1))) void*)(p)
#define LDSP(p) (__attribute__((address_space(3))) void*)(p)

static constexpr int BS   = 8;
static constexpr int SEQ  = 2048;
static constexpr int DIN  = 4096;
static constexpr int DOUT = 4096;
static constexpr int NSK  = 8;
static constexpr int RANK = 16;
static constexpr int MTOT = BS * SEQ;           // 16384

static __device__ __forceinline__ bf16x8 cvt8(float4 v0, float4 v1) {
    bf16x8 o;
    o[0] = (bf16_t)v0.x; o[1] = (bf16_t)v0.y; o[2] = (bf16_t)v0.z; o[3] = (bf16_t)v0.w;
    o[4] = (bf16_t)v1.x; o[5] = (bf16_t)v1.y; o[6] = (bf16_t)v1.z; o[7] = (bf16_t)v1.w;
    return o;
}

// ------------------------------------------------------------------
// Kernel 1: mixing weights -> Abt (bf16 [b][16][4096]) and
//           Btp (bf16 [b][4096][32], r>=16 zero)
// ------------------------------------------------------------------
__global__ __launch_bounds__(256) void mix_kernel(
    const float* __restrict__ logits, const int* __restrict__ task_ids,
    const float* __restrict__ lora_a, const float* __restrict__ lora_b,
    bf16_t* __restrict__ Abt, bf16_t* __restrict__ Btp) {
    int b = blockIdx.y;
    int c = blockIdx.x;
    int tid = threadIdx.x;

    int t = task_ids[b];
    float w[NSK]; float sum = 0.f;
#pragma unroll
    for (int s = 0; s < NSK; ++s) {
        float lg = logits[t * NSK + s];
        float sg = 1.f / (1.f + __expf(-lg));
        w[s] = sg; sum += sg;
    }
    float inv = 1.f / (sum + 1e-12f);
#pragma unroll
    for (int s = 0; s < NSK; ++s) w[s] *= inv;

    {
        int r = tid & 15, kk = tid >> 4;
#pragma unroll
        for (int i = 0; i < 4; ++i) {
            int k = c * 64 + i * 16 + kk;
            float acc = 0.f;
#pragma unroll
            for (int s = 0; s < NSK; ++s)
                acc += w[s] * lora_a[((size_t)s * DIN + k) * RANK + r];
            Abt[((size_t)b * RANK + r) * DIN + k] = (bf16_t)acc;
        }
    }
    {
        int n = c * 64 + (tid & 63);
        int r0 = tid >> 6;
#pragma unroll
        for (int i = 0; i < 4; ++i) {
            int rr = r0 + i * 4;
            float acc = 0.f;
#pragma unroll
            for (int s = 0; s < NSK; ++s)
                acc += w[s] * lora_b[((size_t)s * RANK + rr) * DOUT + n];
            Btp[((size_t)b * DOUT + n) * 32 + rr] = (bf16_t)acc;
            Btp[((size_t)b * DOUT + n) * 32 + 16 + rr] = (bf16_t)0.f;
        }
    }
}

// ------------------------------------------------------------------
// Kernel 2: W f32 -> bf16
// ------------------------------------------------------------------
__global__ __launch_bounds__(256) void convw_kernel(const float* __restrict__ W,
                                                    bf16_t* __restrict__ Wb) {
    size_t g = (size_t)blockIdx.x * 256 + threadIdx.x;
    const float4* src = (const float4*)W;
    float4 v0 = src[g * 2], v1 = src[g * 2 + 1];
    *(bf16x8*)(Wb + g * 8) = cvt8(v0, v1);
}

// ------------------------------------------------------------------
// Kernel 3: fused x->bf16 conversion + t = (x @ A_mix)/16, padded to K=32
// ------------------------------------------------------------------
template<bool XPRE>
__global__ __launch_bounds__(256) void tconv_kernel(
    const float* __restrict__ x, const bf16_t* __restrict__ Abt,
    bf16_t* __restrict__ xb, bf16_t* __restrict__ tpad) {
    __shared__ __align__(16) bf16_t As[64 * 64];
    __shared__ __align__(16) bf16_t Aa[16 * 64];

    int row0 = blockIdx.x * 64;
    int b = row0 >> 11;
    int tid = threadIdx.x;
    int w = tid >> 6, l = tid & 63;
    const bf16_t* Ab = Abt + (size_t)b * RANK * DIN;

    f32x4 acc = {0.f, 0.f, 0.f, 0.f};

    for (int k0 = 0; k0 < DIN; k0 += 64) {
#pragma unroll
        for (int i = 0; i < 2; ++i) {
            int flat = i * 256 + tid;
            int row = flat >> 3, c8 = flat & 7;
            const float* src = x + (size_t)(row0 + row) * DIN + k0 + c8 * 8;
            float4 v0 = *(const float4*)src;
            float4 v1 = *(const float4*)(src + 4);
            bf16x8 o = cvt8(v0, v1);
            *(bf16x8*)(&As[flat * 8]) = o;
            if (XPRE)
                *(bf16x8*)(xb + (size_t)(row0 + row) * DIN + k0 + c8 * 8) = o;
        }
        if (tid < 128) {
            int r = tid >> 3, c8 = tid & 7;
            __builtin_amdgcn_global_load_lds(GLP(Ab + (size_t)r * DIN + k0 + c8 * 8),
                                             LDSP(&Aa[tid * 8]), 16, 0, 0);
        }
        __syncthreads();
#pragma unroll
        for (int s = 0; s < 2; ++s) {
            int kr = s * 32 + (l >> 4) * 8;
            bf16x8 a = *(const bf16x8*)(&As[(w * 16 + (l & 15)) * 64 + kr]);
            bf16x8 bb = *(const bf16x8*)(&Aa[(l & 15) * 64 + kr]);
            acc = __builtin_amdgcn_mfma_f32_16x16x32_bf16(a, bb, acc, 0, 0, 0);
        }
        __syncthreads();
    }
    int r = l & 15;
    int rowb = w * 16 + (l >> 4) * 4;
#pragma unroll
    for (int j = 0; j < 4; ++j) {
        int gm = row0 + rowb + j;
        tpad[(size_t)gm * 32 + r] = (bf16_t)(acc[j] * 0.0625f);
        tpad[(size_t)gm * 32 + 16 + r] = (bf16_t)0.f;
    }
}

// ------------------------------------------------------------------
// Kernel 4: 256x128 tile, BK=64, 8 waves (4Mx2N), 3-buffer LDS rotation,
//   ONE barrier + one (free) counted vmcnt per K-tile.
//   Iter j:  barrier                     // readers of buf[(j-1)%3] done
//            stage(j+2 -> buf[(j+2)%3])  // == buf[(j-1)%3], safe
//            vmcnt(6)                    // stage(j+1) landed (1-tile lead)
//            body: 16 ds_read + 32 MFMA  // buf[j%3], landed a tile ago
//   Adapter (K=32) staged at j=62 into buf[1]; applied after the loop.
// ------------------------------------------------------------------
#define SBAR   __builtin_amdgcn_s_barrier()
#define SCHEDB __builtin_amdgcn_sched_barrier(0)
#define VMG(TXT) asm volatile("s_waitcnt " TXT ::: "memory")

__global__ __launch_bounds__(512, 2) void gemm3_kernel(
    const bf16_t* __restrict__ xb, const bf16_t* __restrict__ Wb,
    const float* __restrict__ bias,
    const bf16_t* __restrict__ tpad, const bf16_t* __restrict__ Btp,
    float* __restrict__ out) {
    __shared__ __align__(16) bf16_t bufA[3][256 * 64];   // 96 KiB
    __shared__ __align__(16) bf16_t bufB[3][128 * 64];   // 48 KiB

    int tid = threadIdx.x;
    int w = tid >> 6, l = tid & 63;
    int wm = w >> 1, wn = w & 1;        // 4M x 2N waves, 64x64 out each
    int l4 = l >> 4, l15 = l & 15;

    // XCD-bijective swizzle: nwg = 2048, 8 XCDs, 256 per XCD
    int orig = blockIdx.x;
    int id = (orig & 7) * 256 + (orig >> 3);
    int mb = id >> 5, nb = id & 31;     // 64 x 32
    int row0 = mb * 256, col0 = nb * 128;
    int b = row0 >> 11;

    f32x4 acc[4][4] = {};

    // per-thread constant source offsets (swizzled chunk), + t*64 per tile
    const bf16_t* aSrc[4];
    const bf16_t* bSrc[2];
#pragma unroll
    for (int ld = 0; ld < 4; ++ld) {
        int flat = ld * 512 + tid;          // 0..2047
        int r = flat >> 3;
        int sc = (flat & 7) ^ (r & 7);
        aSrc[ld] = xb + (size_t)(row0 + r) * DIN + sc * 8;
    }
#pragma unroll
    for (int ld = 0; ld < 2; ++ld) {
        int flat = ld * 512 + tid;          // 0..1023
        int r = flat >> 3;
        int sc = (flat & 7) ^ (r & 7);
        bSrc[ld] = Wb + (size_t)(col0 + r) * DIN + sc * 8;
    }

    auto stage = [&](int t) {
        int c = t % 3;
        int k0 = t * 64;
#pragma unroll
        for (int ld = 0; ld < 4; ++ld) {
            int flat = ld * 512 + tid;
            __builtin_amdgcn_global_load_lds(GLP(aSrc[ld] + k0),
                                             LDSP(&bufA[c][flat * 8]), 16, 0, 0);
        }
#pragma unroll
        for (int ld = 0; ld < 2; ++ld) {
            int flat = ld * 512 + tid;
            __builtin_amdgcn_global_load_lds(GLP(bSrc[ld] + k0),
                                             LDSP(&bufB[c][flat * 8]), 16, 0, 0);
        }
    };
    auto stageAdp = [&]() {   // adapter tiles (linear, K=32) into buf 1
#pragma unroll
        for (int ld = 0; ld < 2; ++ld) {
            int flat = ld * 512 + tid;      // 0..1023
            int r = flat >> 2, c4 = flat & 3;
            __builtin_amdgcn_global_load_lds(
                GLP(tpad + (size_t)(row0 + r) * 32 + c4 * 8),
                LDSP(&bufA[1][flat * 8]), 16, 0, 0);
        }
        {
            int r = tid >> 2, c4 = tid & 3;   // 512 chunks
            __builtin_amdgcn_global_load_lds(
                GLP(Btp + ((size_t)b * DOUT + col0 + r) * 32 + c4 * 8),
                LDSP(&bufB[1][tid * 8]), 16, 0, 0);
        }
    };

    auto loadAfrag = [&](int c, int i, int s) {
        int row = wm * 64 + i * 16 + l15;
        int ch = (s * 4 + l4) ^ (row & 7);
        return *(const bf16x8*)(&bufA[c][row * 64 + ch * 8]);
    };
    auto loadBfrag = [&](int c, int jj, int s) {
        int row = wn * 64 + jj * 16 + l15;
        int ch = (s * 4 + l4) ^ (row & 7);
        return *(const bf16x8*)(&bufB[c][row * 64 + ch * 8]);
    };

    // prologue: stage tiles 0 and 1 (12 loads in flight)
    stage(0);
    stage(1);

#pragma unroll 1
    for (int j = 0; j < 64; ++j) {
        int c = j % 3;
        SCHEDB; SBAR; SCHEDB;        // readers of buf[(j-1)%3] are done
        if (j < 62)       stage(j + 2);
        else if (j == 62) stageAdp();
        if (j < 63) { VMG("vmcnt(6)"); } else { VMG("vmcnt(3)"); }
        SCHEDB;

        // ---- straight-line body: 16 ds_read + 32 MFMA ----
        bf16x8 aL[2][2], aH[2][2], bL[2][2], bH[2][2];
#pragma unroll
        for (int i = 0; i < 2; ++i)
#pragma unroll
            for (int s = 0; s < 2; ++s) aL[i][s] = loadAfrag(c, i, s);
#pragma unroll
        for (int jj = 0; jj < 2; ++jj)
#pragma unroll
            for (int s = 0; s < 2; ++s) bL[jj][s] = loadBfrag(c, jj, s);
        // quadrant (0..1, 0..1)
#pragma unroll
        for (int s = 0; s < 2; ++s)
#pragma unroll
            for (int i = 0; i < 2; ++i)
#pragma unroll
                for (int jj = 0; jj < 2; ++jj)
                    acc[i][jj] = __builtin_amdgcn_mfma_f32_16x16x32_bf16(
                        aL[i][s], bL[jj][s], acc[i][jj], 0, 0, 0);
#pragma unroll
        for (int jj = 0; jj < 2; ++jj)
#pragma unroll
            for (int s = 0; s < 2; ++s) bH[jj][s] = loadBfrag(c, 2 + jj, s);
        // quadrant (0..1, 2..3)
#pragma unroll
        for (int s = 0; s < 2; ++s)
#pragma unroll
            for (int i = 0; i < 2; ++i)
#pragma unroll
                for (int jj = 0; jj < 2; ++jj)
                    acc[i][2 + jj] = __builtin_amdgcn_mfma_f32_16x16x32_bf16(
                        aL[i][s], bH[jj][s], acc[i][2 + jj], 0, 0, 0);
#pragma unroll
        for (int i = 0; i < 2; ++i)
#pragma unroll
            for (int s = 0; s < 2; ++s) aH[i][s] = loadAfrag(c, 2 + i, s);
        // quadrant (2..3, 2..3)
#pragma unroll
        for (int s = 0; s < 2; ++s)
#pragma unroll
            for (int i = 0; i < 2; ++i)
#pragma unroll
                for (int jj = 0; jj < 2; ++jj)
                    acc[2 + i][2 + jj] = __builtin_amdgcn_mfma_f32_16x16x32_bf16(
                        aH[i][s], bH[jj][s], acc[2 + i][2 + jj], 0, 0, 0);
        // quadrant (2..3, 0..1) — bL still live
#pragma unroll
        for (int s = 0; s < 2; ++s)
#pragma unroll
            for (int i = 0; i < 2; ++i)
#pragma unroll
                for (int jj = 0; jj < 2; ++jj)
                    acc[2 + i][jj] = __builtin_amdgcn_mfma_f32_16x16x32_bf16(
                        aH[i][s], bL[jj][s], acc[2 + i][jj], 0, 0, 0);
    }

    // drain adapter loads, sync, adapter K=32 MFMA from buf 1 (linear)
    VMG("vmcnt(0)"); SCHEDB; SBAR; SCHEDB;
    {
        bf16x8 aa[4], bb[4];
#pragma unroll
        for (int i = 0; i < 4; ++i) {
            int row = wm * 64 + i * 16 + l15;
            aa[i] = *(const bf16x8*)(&bufA[1][row * 32 + l4 * 8]);
        }
#pragma unroll
        for (int jj = 0; jj < 4; ++jj) {
            int row = wn * 64 + jj * 16 + l15;
            bb[jj] = *(const bf16x8*)(&bufB[1][row * 32 + l4 * 8]);
        }
#pragma unroll
        for (int i = 0; i < 4; ++i)
#pragma unroll
            for (int jj = 0; jj < 4; ++jj)
                acc[i][jj] = __builtin_amdgcn_mfma_f32_16x16x32_bf16(
                    aa[i], bb[jj], acc[i][jj], 0, 0, 0);
    }

    // ---- epilogue: + bias, store f32 ----
#pragma unroll
    for (int i = 0; i < 4; ++i) {
        int gm = row0 + wm * 64 + i * 16 + l4 * 4;
#pragma unroll
        for (int jj = 0; jj < 4; ++jj) {
            int gn = col0 + wn * 64 + jj * 16 + l15;
            float bsv = bias[gn];
#pragma unroll
            for (int q = 0; q < 4; ++q)
                out[(size_t)(gm + q) * DOUT + gn] = acc[i][jj][q] + bsv;
        }
    }
}

// ------------------------------------------------------------------
// Fallback GEMM (m97 structure) for small-workspace paths
// ------------------------------------------------------------------
template<bool WPRE>
__global__ __launch_bounds__(256) void gemm_kernel(
    const float* __restrict__ xf,
    const float* __restrict__ Wf, const bf16_t* __restrict__ Wb,
    const float* __restrict__ bias,
    const bf16_t* __restrict__ tpad, const bf16_t* __restrict__ Btp,
    float* __restrict__ out) {
    __shared__ __align__(16) bf16_t As[128 * 64];
    __shared__ __align__(16) bf16_t Bs[128 * 64];

    int orig = blockIdx.x;
    int id = (orig & 7) * 512 + (orig >> 3);
    int mb = id >> 5, nb = id & 31;
    int row0 = mb * 128, col0 = nb * 128;
    int b = row0 >> 11;

    int tid = threadIdx.x;
    int w = tid >> 6, l = tid & 63;
    int wm = w >> 1, wn = w & 1;

    f32x4 acc[4][4] = {};

    for (int k0 = 0; k0 < DIN; k0 += 64) {
#pragma unroll
        for (int i = 0; i < 4; ++i) {
            int flat = i * 256 + tid;
            int row = flat >> 3, c8 = flat & 7;
            const float* src = xf + (size_t)(row0 + row) * DIN + k0 + c8 * 8;
            float4 v0 = *(const float4*)src;
            float4 v1 = *(const float4*)(src + 4);
            *(bf16x8*)(&As[flat * 8]) = cvt8(v0, v1);
        }
        if constexpr (WPRE) {
#pragma unroll
            for (int i = 0; i < 4; ++i) {
                int flat = i * 256 + tid;
                int row = flat >> 3, c8 = flat & 7;
                __builtin_amdgcn_global_load_lds(
                    GLP(Wb + (size_t)(col0 + row) * DIN + k0 + c8 * 8),
                    LDSP(&Bs[flat * 8]), 16, 0, 0);
            }
        } else {
#pragma unroll
            for (int i = 0; i < 4; ++i) {
                int flat = i * 256 + tid;
                int row = flat >> 3, c8 = flat & 7;
                const float* src = Wf + (size_t)(col0 + row) * DIN + k0 + c8 * 8;
                float4 v0 = *(const float4*)src;
                float4 v1 = *(const float4*)(src + 4);
                *(bf16x8*)(&Bs[flat * 8]) = cvt8(v0, v1);
            }
        }
        __syncthreads();
#pragma unroll
        for (int s = 0; s < 2; ++s) {
            int kr = s * 32 + (l >> 4) * 8;
            bf16x8 a[4], bf[4];
#pragma unroll
            for (int i = 0; i < 4; ++i)
                a[i] = *(const bf16x8*)(&As[(wm * 64 + i * 16 + (l & 15)) * 64 + kr]);
#pragma unroll
            for (int j = 0; j < 4; ++j)
                bf[j] = *(const bf16x8*)(&Bs[(wn * 64 + j * 16 + (l & 15)) * 64 + kr]);
#pragma unroll
            for (int i = 0; i < 4; ++i)
#pragma unroll
                for (int j = 0; j < 4; ++j)
                    acc[i][j] = __builtin_amdgcn_mfma_f32_16x16x32_bf16(a[i], bf[j], acc[i][j], 0, 0, 0);
        }
        __syncthreads();
    }

    {
#pragma unroll
        for (int i = 0; i < 2; ++i) {
            int flat = i * 256 + tid;
            int row = flat >> 2, c8 = flat & 3;
            __builtin_amdgcn_global_load_lds(
                GLP(tpad + (size_t)(row0 + row) * 32 + c8 * 8),
                LDSP(&As[flat * 8]), 16, 0, 0);
            __builtin_amdgcn_global_load_lds(
                GLP(Btp + ((size_t)b * DOUT + col0 + row) * 32 + c8 * 8),
                LDSP(&Bs[flat * 8]), 16, 0, 0);
        }
        __syncthreads();
        int kr = (l >> 4) * 8;
        bf16x8 a[4], bf[4];
#pragma unroll
        for (int i = 0; i < 4; ++i)
            a[i] = *(const bf16x8*)(&As[(wm * 64 + i * 16 + (l & 15)) * 32 + kr]);
#pragma unroll
        for (int j = 0; j < 4; ++j)
            bf[j] = *(const bf16x8*)(&Bs[(wn * 64 + j * 16 + (l & 15)) * 32 + kr]);
#pragma unroll
        for (int i = 0; i < 4; ++i)
#pragma unroll
            for (int j = 0; j < 4; ++j)
                acc[i][j] = __builtin_amdgcn_mfma_f32_16x16x32_bf16(a[i], bf[j], acc[i][j], 0, 0, 0);
    }

#pragma unroll
    for (int i = 0; i < 4; ++i) {
        int gm = row0 + wm * 64 + i * 16 + (l >> 4) * 4;
#pragma unroll
        for (int j = 0; j < 4; ++j) {
            int gn = col0 + wn * 64 + j * 16 + (l & 15);
            float bs = bias[gn];
#pragma unroll
            for (int q = 0; q < 4; ++q)
                out[(size_t)(gm + q) * DOUT + gn] = acc[i][j][q] + bs;
        }
    }
}

// ------------------------------------------------------------------
extern "C" void kernel_launch(void* const* d_in, const int* in_sizes, int n_in,
                              void* d_out, int out_size, void* d_ws, size_t ws_size,
                              hipStream_t stream) {
    const float* x        = (const float*)d_in[0];
    const int*   task_ids = (const int*)d_in[1];
    const float* W        = (const float*)d_in[2];
    const float* bias     = (const float*)d_in[3];
    const float* logits   = (const float*)d_in[4];
    const float* lora_a   = (const float*)d_in[5];
    const float* lora_b   = (const float*)d_in[6];
    float* out = (float*)d_out;

    char* ws = (char*)d_ws;
    size_t off = 0;
    auto alloc = [&](size_t bytes) {
        char* p = ws + off;
        off += (bytes + 255) & ~(size_t)255;
        return p;
    };
    bf16_t* Abt  = (bf16_t*)alloc((size_t)BS * RANK * DIN * 2);
    bf16_t* Btp  = (bf16_t*)alloc((size_t)BS * DOUT * 32 * 2);
    bf16_t* tpad = (bf16_t*)alloc((size_t)MTOT * 32 * 2);
    bf16_t* Wb   = (bf16_t*)alloc((size_t)DOUT * DIN * 2);
    size_t w_end = off;
    bf16_t* xb   = (bf16_t*)alloc((size_t)MTOT * DIN * 2);
    size_t full_end = off;

    bool wpre = ws_size >= w_end;
    bool xpre = ws_size >= full_end;

    mix_kernel<<<dim3(64, 8), 256, 0, stream>>>(logits, task_ids, lora_a, lora_b, Abt, Btp);
    if (wpre)
        convw_kernel<<<(DOUT * DIN / 8) / 256, 256, 0, stream>>>(W, Wb);
    if (xpre)
        tconv_kernel<true><<<MTOT / 64, 256, 0, stream>>>(x, Abt, xb, tpad);
    else
        tconv_kernel<false><<<MTOT / 64, 256, 0, stream>>>(x, Abt, nullptr, tpad);

    if (xpre) {
        int nblk = (MTOT / 256) * (DOUT / 128);   // 2048
        gemm3_kernel<<<nblk, 512, 0, stream>>>(xb, Wb, bias, tpad, Btp, out);
    } else {
        int nblk = (MTOT / 128) * (DOUT / 128);   // 4096
        if (wpre)
            gemm_kernel<true><<<nblk, 256, 0, stream>>>(x, W, Wb, bias, tpad, Btp, out);
        else
            gemm_kernel<false><<<nblk, 256, 0, stream>>>(x, W, Wb, bias, tpad, Btp, out);
    }
}

// Round 15
// 602.381 us; speedup vs baseline: 1.6364x; 1.6364x over previous
//
#include <hip/hip_runtime.h>
#include <hip/hip_bf16.h>
#include <cstdint>
#include <cstddef>

typedef __bf16 bf16_t;
typedef __bf16 bf16x8 __attribute__((ext_vector_type(8)));
typedef float f32x4 __attribute__((ext_vector_type(4)));

#define GLP(p)  (const __attribute__((address_space(1))) void*)(p)
#define LDSP(p) (__attribute__((address_space(3))) void*)(p)

static constexpr int BS   = 8;
static constexpr int SEQ  = 2048;
static constexpr int DIN  = 4096;
static constexpr int DOUT = 4096;
static constexpr int NSK  = 8;
static constexpr int RANK = 16;
static constexpr int MTOT = BS * SEQ;           // 16384

static __device__ __forceinline__ bf16x8 cvt8(float4 v0, float4 v1) {
    bf16x8 o;
    o[0] = (bf16_t)v0.x; o[1] = (bf16_t)v0.y; o[2] = (bf16_t)v0.z; o[3] = (bf16_t)v0.w;
    o[4] = (bf16_t)v1.x; o[5] = (bf16_t)v1.y; o[6] = (bf16_t)v1.z; o[7] = (bf16_t)v1.w;
    return o;
}

// ------------------------------------------------------------------
// Kernel 1: mixing weights -> Abt (A^T mixed, bf16 [b][16][4096]) and
//           Btp (B mixed transposed+padded, bf16 [b][4096][32], r>=16 zero)
// ------------------------------------------------------------------
__global__ __launch_bounds__(256) void mix_kernel(
    const float* __restrict__ logits, const int* __restrict__ task_ids,
    const float* __restrict__ lora_a, const float* __restrict__ lora_b,
    bf16_t* __restrict__ Abt, bf16_t* __restrict__ Btp) {
    int b = blockIdx.y;
    int c = blockIdx.x;
    int tid = threadIdx.x;

    int t = task_ids[b];
    float w[NSK]; float sum = 0.f;
#pragma unroll
    for (int s = 0; s < NSK; ++s) {
        float lg = logits[t * NSK + s];
        float sg = 1.f / (1.f + __expf(-lg));
        w[s] = sg; sum += sg;
    }
    float inv = 1.f / (sum + 1e-12f);
#pragma unroll
    for (int s = 0; s < NSK; ++s) w[s] *= inv;

    {
        int r = tid & 15, kk = tid >> 4;
#pragma unroll
        for (int i = 0; i < 4; ++i) {
            int k = c * 64 + i * 16 + kk;
            float acc = 0.f;
#pragma unroll
            for (int s = 0; s < NSK; ++s)
                acc += w[s] * lora_a[((size_t)s * DIN + k) * RANK + r];
            Abt[((size_t)b * RANK + r) * DIN + k] = (bf16_t)acc;
        }
    }
    {
        int n = c * 64 + (tid & 63);
        int r0 = tid >> 6;
#pragma unroll
        for (int i = 0; i < 4; ++i) {
            int rr = r0 + i * 4;
            float acc = 0.f;
#pragma unroll
            for (int s = 0; s < NSK; ++s)
                acc += w[s] * lora_b[((size_t)s * RANK + rr) * DOUT + n];
            Btp[((size_t)b * DOUT + n) * 32 + rr] = (bf16_t)acc;
            Btp[((size_t)b * DOUT + n) * 32 + 16 + rr] = (bf16_t)0.f;
        }
    }
}

// ------------------------------------------------------------------
// Kernel 2: W f32 -> bf16
// ------------------------------------------------------------------
__global__ __launch_bounds__(256) void convw_kernel(const float* __restrict__ W,
                                                    bf16_t* __restrict__ Wb) {
    size_t g = (size_t)blockIdx.x * 256 + threadIdx.x;
    const float4* src = (const float4*)W;
    float4 v0 = src[g * 2], v1 = src[g * 2 + 1];
    *(bf16x8*)(Wb + g * 8) = cvt8(v0, v1);
}

// ------------------------------------------------------------------
// Kernel 3: fused x->bf16 conversion + t = (x @ A_mix)/16, padded to K=32
// ------------------------------------------------------------------
template<bool XPRE>
__global__ __launch_bounds__(256) void tconv_kernel(
    const float* __restrict__ x, const bf16_t* __restrict__ Abt,
    bf16_t* __restrict__ xb, bf16_t* __restrict__ tpad) {
    __shared__ __align__(16) bf16_t As[64 * 64];
    __shared__ __align__(16) bf16_t Aa[16 * 64];

    int row0 = blockIdx.x * 64;
    int b = row0 >> 11;
    int tid = threadIdx.x;
    int w = tid >> 6, l = tid & 63;
    const bf16_t* Ab = Abt + (size_t)b * RANK * DIN;

    f32x4 acc = {0.f, 0.f, 0.f, 0.f};

    for (int k0 = 0; k0 < DIN; k0 += 64) {
#pragma unroll
        for (int i = 0; i < 2; ++i) {
            int flat = i * 256 + tid;
            int row = flat >> 3, c8 = flat & 7;
            const float* src = x + (size_t)(row0 + row) * DIN + k0 + c8 * 8;
            float4 v0 = *(const float4*)src;
            float4 v1 = *(const float4*)(src + 4);
            bf16x8 o = cvt8(v0, v1);
            *(bf16x8*)(&As[flat * 8]) = o;
            if (XPRE)
                *(bf16x8*)(xb + (size_t)(row0 + row) * DIN + k0 + c8 * 8) = o;
        }
        if (tid < 128) {
            int r = tid >> 3, c8 = tid & 7;
            __builtin_amdgcn_global_load_lds(GLP(Ab + (size_t)r * DIN + k0 + c8 * 8),
                                             LDSP(&Aa[tid * 8]), 16, 0, 0);
        }
        __syncthreads();
#pragma unroll
        for (int s = 0; s < 2; ++s) {
            int kr = s * 32 + (l >> 4) * 8;
            bf16x8 a = *(const bf16x8*)(&As[(w * 16 + (l & 15)) * 64 + kr]);
            bf16x8 bb = *(const bf16x8*)(&Aa[(l & 15) * 64 + kr]);
            acc = __builtin_amdgcn_mfma_f32_16x16x32_bf16(a, bb, acc, 0, 0, 0);
        }
        __syncthreads();
    }
    int r = l & 15;
    int rowb = w * 16 + (l >> 4) * 4;
#pragma unroll
    for (int j = 0; j < 4; ++j) {
        int gm = row0 + rowb + j;
        tpad[(size_t)gm * 32 + r] = (bf16_t)(acc[j] * 0.0625f);
        tpad[(size_t)gm * 32 + 16 + r] = (bf16_t)0.f;
    }
}

// ------------------------------------------------------------------
// Kernel 4: 256x256 pipelined GEMM, TWO barriers per K-tile (race-free).
//   out = xb @ Wb^T + bias + tpad @ Btp^T
//   LDS 128 KiB: [buf(2)][op(2)][256][64] bf16, XOR-swizzled chunks.
//   Iteration:
//     s_barrier                  // #1: all waves done READING buf[c^1]
//     stageA(j+1 -> buf[c^1])    // now safe to write
//     s_waitcnt vmcnt(4)         // tile j's 8 loads landed; 4 new in flight
//     s_barrier                  // #2: every wave's tile-j stage landed
//     straight-line body: 24 ds_read_b128 + 64 MFMA + stageB(j+1)
// ------------------------------------------------------------------
struct P8 { int wm, wn, l4, l15, l; };

__device__ __forceinline__ const bf16x8* ldsAddr(const bf16_t* buf, int row, int g) {
    return (const bf16x8*)(buf + row * 64 + ((g ^ (row & 7)) << 3));
}

__global__ __launch_bounds__(512, 2) void gemm8_kernel(
    const bf16_t* __restrict__ xb, const bf16_t* __restrict__ Wb,
    const float* __restrict__ bias,
    const bf16_t* __restrict__ tpad, const bf16_t* __restrict__ Btp,
    float* __restrict__ out) {
    __shared__ __align__(16) bf16_t lds[2][2][256 * 64];   // 128 KiB

    int tid = threadIdx.x;
    int w = tid >> 6, l = tid & 63;
    P8 p{w >> 2, w & 3, l >> 4, l & 15, l};

    // XCD-bijective swizzle: nwg = 1024, 8 XCDs, 128 per XCD
    int orig = blockIdx.x;
    int id = (orig & 7) * 128 + (orig >> 3);
    int mb = id >> 4, nb = id & 15;
    int row0 = mb * 256, col0 = nb * 256;
    int b = row0 >> 11;

    f32x4 acc[8][4] = {};

    auto stageA = [&](int kt, int c) {
        int k0 = kt * 64;
#pragma unroll
        for (int g = 0; g < 4; ++g) {
            int row = w * 32 + g * 8 + (l >> 3);
            int sc = (l & 7) ^ (row & 7);
            __builtin_amdgcn_global_load_lds(
                GLP(xb + (size_t)(row0 + row) * DIN + k0 + sc * 8),
                LDSP(&lds[c][0][(w * 32 + g * 8) * 64 + l * 8]), 16, 0, 0);
        }
    };
    auto stageB = [&](int kt, int c) {
        int k0 = kt * 64;
#pragma unroll
        for (int g = 0; g < 4; ++g) {
            int row = w * 32 + g * 8 + (l >> 3);
            int sc = (l & 7) ^ (row & 7);
            __builtin_amdgcn_global_load_lds(
                GLP(Wb + (size_t)(col0 + row) * DIN + k0 + sc * 8),
                LDSP(&lds[c][1][(w * 32 + g * 8) * 64 + l * 8]), 16, 0, 0);
        }
    };
    auto stageAdp = [&]() {
#pragma unroll
        for (int g = 0; g < 2; ++g) {
            int flat = g * 512 + tid;
            int row = flat >> 2, ch = flat & 3;
            __builtin_amdgcn_global_load_lds(
                GLP(tpad + (size_t)(row0 + row) * 32 + ch * 8),
                LDSP(&lds[0][0][flat * 8]), 16, 0, 0);
        }
#pragma unroll
        for (int g = 0; g < 2; ++g) {
            int flat = g * 512 + tid;
            int row = flat >> 2, ch = flat & 3;
            __builtin_amdgcn_global_load_lds(
                GLP(Btp + ((size_t)b * DOUT + col0 + row) * 32 + ch * 8),
                LDSP(&lds[0][1][flat * 8]), 16, 0, 0);
        }
    };

    auto loadA = [&](const bf16_t* bufA, int MH, bf16x8 (&ar)[4][2]) {
#pragma unroll
        for (int i = 0; i < 4; ++i) {
            int row = p.wm * 128 + MH * 64 + i * 16 + p.l15;
#pragma unroll
            for (int s = 0; s < 2; ++s)
                ar[i][s] = *ldsAddr(bufA, row, s * 4 + p.l4);
        }
    };
    auto loadB = [&](const bf16_t* bufB, int NH, bf16x8 (&br)[2][2]) {
#pragma unroll
        for (int jj = 0; jj < 2; ++jj) {
            int row = p.wn * 64 + NH * 32 + jj * 16 + p.l15;
#pragma unroll
            for (int s = 0; s < 2; ++s)
                br[jj][s] = *ldsAddr(bufB, row, s * 4 + p.l4);
        }
    };

    // prologue: stage ktile 0 -> buf0 (8 loads in flight)
    stageA(0, 0);
    stageB(0, 0);

#pragma unroll 1
    for (int j = 0; j < 64; ++j) {
        int c = j & 1;
        // barrier #1: all waves have finished reading buf[c^1] (iter j-1 body)
        __builtin_amdgcn_sched_barrier(0);
        __builtin_amdgcn_s_barrier();
        __builtin_amdgcn_sched_barrier(0);
        // now safe to write buf[c^1]
        if (j < 63) stageA(j + 1, c ^ 1);
        else        stageAdp();
        // wait for THIS tile's 8 loads (oldest) — the 4 new stay in flight
        asm volatile("s_waitcnt vmcnt(4)" ::: "memory");
        __builtin_amdgcn_sched_barrier(0);
        // barrier #2: every wave's tile-j stage has landed
        __builtin_amdgcn_s_barrier();
        __builtin_amdgcn_sched_barrier(0);

        const bf16_t* bufA = &lds[c][0][0];
        const bf16_t* bufB = &lds[c][1][0];

        bf16x8 a0[4][2], a1[4][2], b0[2][2], b1[2][2];
        loadA(bufA, 0, a0);
        loadB(bufB, 0, b0);
        if (j < 63) stageB(j + 1, c ^ 1);

        // quadrant (0,0)
#pragma unroll
        for (int s = 0; s < 2; ++s)
#pragma unroll
            for (int i = 0; i < 4; ++i)
#pragma unroll
                for (int jj = 0; jj < 2; ++jj)
                    acc[i][jj] = __builtin_amdgcn_mfma_f32_16x16x32_bf16(
                        a0[i][s], b0[jj][s], acc[i][jj], 0, 0, 0);
        loadB(bufB, 1, b1);
        // quadrant (0,1)
#pragma unroll
        for (int s = 0; s < 2; ++s)
#pragma unroll
            for (int i = 0; i < 4; ++i)
#pragma unroll
                for (int jj = 0; jj < 2; ++jj)
                    acc[i][2 + jj] = __builtin_amdgcn_mfma_f32_16x16x32_bf16(
                        a0[i][s], b1[jj][s], acc[i][2 + jj], 0, 0, 0);
        loadA(bufA, 1, a1);
        // quadrant (1,1)
#pragma unroll
        for (int s = 0; s < 2; ++s)
#pragma unroll
            for (int i = 0; i < 4; ++i)
#pragma unroll
                for (int jj = 0; jj < 2; ++jj)
                    acc[4 + i][2 + jj] = __builtin_amdgcn_mfma_f32_16x16x32_bf16(
                        a1[i][s], b1[jj][s], acc[4 + i][2 + jj], 0, 0, 0);
        // quadrant (1,0) — b0 still live, no reload
#pragma unroll
        for (int s = 0; s < 2; ++s)
#pragma unroll
            for (int i = 0; i < 4; ++i)
#pragma unroll
                for (int jj = 0; jj < 2; ++jj)
                    acc[4 + i][jj] = __builtin_amdgcn_mfma_f32_16x16x32_bf16(
                        a1[i][s], b0[jj][s], acc[4 + i][jj], 0, 0, 0);
    }

    // drain adapter loads, sync, then the K=32 adapter MFMA step (buf0, linear)
    asm volatile("s_waitcnt vmcnt(0)" ::: "memory");
    __builtin_amdgcn_sched_barrier(0);
    __builtin_amdgcn_s_barrier();
    __builtin_amdgcn_sched_barrier(0);
    {
        const bf16_t* A0 = &lds[0][0][0];
        const bf16_t* B0 = &lds[0][1][0];
        bf16x8 aa[8]; bf16x8 bb[4];
#pragma unroll
        for (int i = 0; i < 8; ++i)
            aa[i] = *(const bf16x8*)(A0 + (p.wm * 128 + i * 16 + p.l15) * 32 + p.l4 * 8);
#pragma unroll
        for (int j = 0; j < 4; ++j)
            bb[j] = *(const bf16x8*)(B0 + (p.wn * 64 + j * 16 + p.l15) * 32 + p.l4 * 8);
#pragma unroll
        for (int i = 0; i < 8; ++i)
#pragma unroll
            for (int j = 0; j < 4; ++j)
                acc[i][j] = __builtin_amdgcn_mfma_f32_16x16x32_bf16(aa[i], bb[j], acc[i][j], 0, 0, 0);
    }

    // ---- epilogue: + bias, store f32 ----
#pragma unroll
    for (int i = 0; i < 8; ++i) {
        int gm = row0 + p.wm * 128 + i * 16 + p.l4 * 4;
#pragma unroll
        for (int j = 0; j < 4; ++j) {
            int gn = col0 + p.wn * 64 + j * 16 + p.l15;
            float bsv = bias[gn];
#pragma unroll
            for (int q = 0; q < 4; ++q)
                out[(size_t)(gm + q) * DOUT + gn] = acc[i][j][q] + bsv;
        }
    }
}

// ------------------------------------------------------------------
// Fallback GEMM (m97 structure) for small-workspace paths
// ------------------------------------------------------------------
template<bool WPRE>
__global__ __launch_bounds__(256) void gemm_kernel(
    const float* __restrict__ xf,
    const float* __restrict__ Wf, const bf16_t* __restrict__ Wb,
    const float* __restrict__ bias,
    const bf16_t* __restrict__ tpad, const bf16_t* __restrict__ Btp,
    float* __restrict__ out) {
    __shared__ __align__(16) bf16_t As[128 * 64];
    __shared__ __align__(16) bf16_t Bs[128 * 64];

    int orig = blockIdx.x;
    int id = (orig & 7) * 512 + (orig >> 3);
    int mb = id >> 5, nb = id & 31;
    int row0 = mb * 128, col0 = nb * 128;
    int b = row0 >> 11;

    int tid = threadIdx.x;
    int w = tid >> 6, l = tid & 63;
    int wm = w >> 1, wn = w & 1;

    f32x4 acc[4][4] = {};

    for (int k0 = 0; k0 < DIN; k0 += 64) {
#pragma unroll
        for (int i = 0; i < 4; ++i) {
            int flat = i * 256 + tid;
            int row = flat >> 3, c8 = flat & 7;
            const float* src = xf + (size_t)(row0 + row) * DIN + k0 + c8 * 8;
            float4 v0 = *(const float4*)src;
            float4 v1 = *(const float4*)(src + 4);
            *(bf16x8*)(&As[flat * 8]) = cvt8(v0, v1);
        }
        if constexpr (WPRE) {
#pragma unroll
            for (int i = 0; i < 4; ++i) {
                int flat = i * 256 + tid;
                int row = flat >> 3, c8 = flat & 7;
                __builtin_amdgcn_global_load_lds(
                    GLP(Wb + (size_t)(col0 + row) * DIN + k0 + c8 * 8),
                    LDSP(&Bs[flat * 8]), 16, 0, 0);
            }
        } else {
#pragma unroll
            for (int i = 0; i < 4; ++i) {
                int flat = i * 256 + tid;
                int row = flat >> 3, c8 = flat & 7;
                const float* src = Wf + (size_t)(col0 + row) * DIN + k0 + c8 * 8;
                float4 v0 = *(const float4*)src;
                float4 v1 = *(const float4*)(src + 4);
                *(bf16x8*)(&Bs[flat * 8]) = cvt8(v0, v1);
            }
        }
        __syncthreads();
#pragma unroll
        for (int s = 0; s < 2; ++s) {
            int kr = s * 32 + (l >> 4) * 8;
            bf16x8 a[4], bf[4];
#pragma unroll
            for (int i = 0; i < 4; ++i)
                a[i] = *(const bf16x8*)(&As[(wm * 64 + i * 16 + (l & 15)) * 64 + kr]);
#pragma unroll
            for (int j = 0; j < 4; ++j)
                bf[j] = *(const bf16x8*)(&Bs[(wn * 64 + j * 16 + (l & 15)) * 64 + kr]);
#pragma unroll
            for (int i = 0; i < 4; ++i)
#pragma unroll
                for (int j = 0; j < 4; ++j)
                    acc[i][j] = __builtin_amdgcn_mfma_f32_16x16x32_bf16(a[i], bf[j], acc[i][j], 0, 0, 0);
        }
        __syncthreads();
    }

    {
#pragma unroll
        for (int i = 0; i < 2; ++i) {
            int flat = i * 256 + tid;
            int row = flat >> 2, c8 = flat & 3;
            __builtin_amdgcn_global_load_lds(
                GLP(tpad + (size_t)(row0 + row) * 32 + c8 * 8),
                LDSP(&As[flat * 8]), 16, 0, 0);
            __builtin_amdgcn_global_load_lds(
                GLP(Btp + ((size_t)b * DOUT + col0 + row) * 32 + c8 * 8),
                LDSP(&Bs[flat * 8]), 16, 0, 0);
        }
        __syncthreads();
        int kr = (l >> 4) * 8;
        bf16x8 a[4], bf[4];
#pragma unroll
        for (int i = 0; i < 4; ++i)
            a[i] = *(const bf16x8*)(&As[(wm * 64 + i * 16 + (l & 15)) * 32 + kr]);
#pragma unroll
        for (int j = 0; j < 4; ++j)
            bf[j] = *(const bf16x8*)(&Bs[(wn * 64 + j * 16 + (l & 15)) * 32 + kr]);
#pragma unroll
        for (int i = 0; i < 4; ++i)
#pragma unroll
            for (int j = 0; j < 4; ++j)
                acc[i][j] = __builtin_amdgcn_mfma_f32_16x16x32_bf16(a[i], bf[j], acc[i][j], 0, 0, 0);
    }

#pragma unroll
    for (int i = 0; i < 4; ++i) {
        int gm = row0 + wm * 64 + i * 16 + (l >> 4) * 4;
#pragma unroll
        for (int j = 0; j < 4; ++j) {
            int gn = col0 + wn * 64 + j * 16 + (l & 15);
            float bs = bias[gn];
#pragma unroll
            for (int q = 0; q < 4; ++q)
                out[(size_t)(gm + q) * DOUT + gn] = acc[i][j][q] + bs;
        }
    }
}

// ------------------------------------------------------------------
extern "C" void kernel_launch(void* const* d_in, const int* in_sizes, int n_in,
                              void* d_out, int out_size, void* d_ws, size_t ws_size,
                              hipStream_t stream) {
    const float* x        = (const float*)d_in[0];
    const int*   task_ids = (const int*)d_in[1];
    const float* W        = (const float*)d_in[2];
    const float* bias     = (const float*)d_in[3];
    const float* logits   = (const float*)d_in[4];
    const float* lora_a   = (const float*)d_in[5];
    const float* lora_b   = (const float*)d_in[6];
    float* out = (float*)d_out;

    char* ws = (char*)d_ws;
    size_t off = 0;
    auto alloc = [&](size_t bytes) {
        char* p = ws + off;
        off += (bytes + 255) & ~(size_t)255;
        return p;
    };
    bf16_t* Abt  = (bf16_t*)alloc((size_t)BS * RANK * DIN * 2);
    bf16_t* Btp  = (bf16_t*)alloc((size_t)BS * DOUT * 32 * 2);
    bf16_t* tpad = (bf16_t*)alloc((size_t)MTOT * 32 * 2);
    bf16_t* Wb   = (bf16_t*)alloc((size_t)DOUT * DIN * 2);
    size_t w_end = off;
    bf16_t* xb   = (bf16_t*)alloc((size_t)MTOT * DIN * 2);
    size_t full_end = off;

    bool wpre = ws_size >= w_end;
    bool xpre = ws_size >= full_end;

    mix_kernel<<<dim3(64, 8), 256, 0, stream>>>(logits, task_ids, lora_a, lora_b, Abt, Btp);
    if (wpre)
        convw_kernel<<<(DOUT * DIN / 8) / 256, 256, 0, stream>>>(W, Wb);
    if (xpre)
        tconv_kernel<true><<<MTOT / 64, 256, 0, stream>>>(x, Abt, xb, tpad);
    else
        tconv_kernel<false><<<MTOT / 64, 256, 0, stream>>>(x, Abt, nullptr, tpad);

    if (xpre) {
        int nblk = (MTOT / 256) * (DOUT / 256);   // 1024
        gemm8_kernel<<<nblk, 512, 0, stream>>>(xb, Wb, bias, tpad, Btp, out);
    } else {
        int nblk = (MTOT / 128) * (DOUT / 128);   // 4096
        if (wpre)
            gemm_kernel<true><<<nblk, 256, 0, stream>>>(x, W, Wb, bias, tpad, Btp, out);
        else
            gemm_kernel<false><<<nblk, 256, 0, stream>>>(x, W, Wb, bias, tpad, Btp, out);
    }
}

// Round 16
// 600.496 us; speedup vs baseline: 1.6415x; 1.0031x over previous
//
#include <hip/hip_runtime.h>
#include <hip/hip_bf16.h>
#include <cstdint>
#include <cstddef>

typedef __bf16 bf16_t;
typedef __bf16 bf16x8 __attribute__((ext_vector_type(8)));
typedef float f32x4 __attribute__((ext_vector_type(4)));

#define GLP(p)  (const __attribute__((address_space(1))) void*)(p)
#define LDSP(p) (__attribute__((address_space(3))) void*)(p)

static constexpr int BS   = 8;
static constexpr int SEQ  = 2048;
static constexpr int DIN  = 4096;
static constexpr int DOUT = 4096;
static constexpr int NSK  = 8;
static constexpr int RANK = 16;
static constexpr int MTOT = BS * SEQ;           // 16384

static __device__ __forceinline__ bf16x8 cvt8(float4 v0, float4 v1) {
    bf16x8 o;
    o[0] = (bf16_t)v0.x; o[1] = (bf16_t)v0.y; o[2] = (bf16_t)v0.z; o[3] = (bf16_t)v0.w;
    o[4] = (bf16_t)v1.x; o[5] = (bf16_t)v1.y; o[6] = (bf16_t)v1.z; o[7] = (bf16_t)v1.w;
    return o;
}

// ------------------------------------------------------------------
// Kernel 1: mixing weights -> Abt (A^T mixed, bf16 [b][16][4096]) and
//           Btp (B mixed transposed+padded, bf16 [b][4096][32], r>=16 zero)
// ------------------------------------------------------------------
__global__ __launch_bounds__(256) void mix_kernel(
    const float* __restrict__ logits, const int* __restrict__ task_ids,
    const float* __restrict__ lora_a, const float* __restrict__ lora_b,
    bf16_t* __restrict__ Abt, bf16_t* __restrict__ Btp) {
    int b = blockIdx.y;
    int c = blockIdx.x;
    int tid = threadIdx.x;

    int t = task_ids[b];
    float w[NSK]; float sum = 0.f;
#pragma unroll
    for (int s = 0; s < NSK; ++s) {
        float lg = logits[t * NSK + s];
        float sg = 1.f / (1.f + __expf(-lg));
        w[s] = sg; sum += sg;
    }
    float inv = 1.f / (sum + 1e-12f);
#pragma unroll
    for (int s = 0; s < NSK; ++s) w[s] *= inv;

    {
        int r = tid & 15, kk = tid >> 4;
#pragma unroll
        for (int i = 0; i < 4; ++i) {
            int k = c * 64 + i * 16 + kk;
            float acc = 0.f;
#pragma unroll
            for (int s = 0; s < NSK; ++s)
                acc += w[s] * lora_a[((size_t)s * DIN + k) * RANK + r];
            Abt[((size_t)b * RANK + r) * DIN + k] = (bf16_t)acc;
        }
    }
    {
        int n = c * 64 + (tid & 63);
        int r0 = tid >> 6;
#pragma unroll
        for (int i = 0; i < 4; ++i) {
            int rr = r0 + i * 4;
            float acc = 0.f;
#pragma unroll
            for (int s = 0; s < NSK; ++s)
                acc += w[s] * lora_b[((size_t)s * RANK + rr) * DOUT + n];
            Btp[((size_t)b * DOUT + n) * 32 + rr] = (bf16_t)acc;
            Btp[((size_t)b * DOUT + n) * 32 + 16 + rr] = (bf16_t)0.f;
        }
    }
}

// ------------------------------------------------------------------
// Kernel 2: W f32 -> bf16
// ------------------------------------------------------------------
__global__ __launch_bounds__(256) void convw_kernel(const float* __restrict__ W,
                                                    bf16_t* __restrict__ Wb) {
    size_t g = (size_t)blockIdx.x * 256 + threadIdx.x;
    const float4* src = (const float4*)W;
    float4 v0 = src[g * 2], v1 = src[g * 2 + 1];
    *(bf16x8*)(Wb + g * 8) = cvt8(v0, v1);
}

// ------------------------------------------------------------------
// Kernel 3: fused x->bf16 conversion + t = (x @ A_mix)/16, padded to K=32
// ------------------------------------------------------------------
template<bool XPRE>
__global__ __launch_bounds__(256) void tconv_kernel(
    const float* __restrict__ x, const bf16_t* __restrict__ Abt,
    bf16_t* __restrict__ xb, bf16_t* __restrict__ tpad) {
    __shared__ __align__(16) bf16_t As[64 * 64];
    __shared__ __align__(16) bf16_t Aa[16 * 64];

    int row0 = blockIdx.x * 64;
    int b = row0 >> 11;
    int tid = threadIdx.x;
    int w = tid >> 6, l = tid & 63;
    const bf16_t* Ab = Abt + (size_t)b * RANK * DIN;

    f32x4 acc = {0.f, 0.f, 0.f, 0.f};

    for (int k0 = 0; k0 < DIN; k0 += 64) {
#pragma unroll
        for (int i = 0; i < 2; ++i) {
            int flat = i * 256 + tid;
            int row = flat >> 3, c8 = flat & 7;
            const float* src = x + (size_t)(row0 + row) * DIN + k0 + c8 * 8;
            float4 v0 = *(const float4*)src;
            float4 v1 = *(const float4*)(src + 4);
            bf16x8 o = cvt8(v0, v1);
            *(bf16x8*)(&As[flat * 8]) = o;
            if (XPRE)
                *(bf16x8*)(xb + (size_t)(row0 + row) * DIN + k0 + c8 * 8) = o;
        }
        if (tid < 128) {
            int r = tid >> 3, c8 = tid & 7;
            __builtin_amdgcn_global_load_lds(GLP(Ab + (size_t)r * DIN + k0 + c8 * 8),
                                             LDSP(&Aa[tid * 8]), 16, 0, 0);
        }
        __syncthreads();
#pragma unroll
        for (int s = 0; s < 2; ++s) {
            int kr = s * 32 + (l >> 4) * 8;
            bf16x8 a = *(const bf16x8*)(&As[(w * 16 + (l & 15)) * 64 + kr]);
            bf16x8 bb = *(const bf16x8*)(&Aa[(l & 15) * 64 + kr]);
            acc = __builtin_amdgcn_mfma_f32_16x16x32_bf16(a, bb, acc, 0, 0, 0);
        }
        __syncthreads();
    }
    int r = l & 15;
    int rowb = w * 16 + (l >> 4) * 4;
#pragma unroll
    for (int j = 0; j < 4; ++j) {
        int gm = row0 + rowb + j;
        tpad[(size_t)gm * 32 + r] = (bf16_t)(acc[j] * 0.0625f);
        tpad[(size_t)gm * 32 + 16 + r] = (bf16_t)0.f;
    }
}

// ------------------------------------------------------------------
// Kernel 4: 256x256 pipelined GEMM, TWO barriers per K-tile (race-free).
//   R7 champion + hoisted stage source pointers (VALU on critical path).
//   Iteration:
//     s_barrier                  // #1: all waves done READING buf[c^1]
//     stageA(j+1 -> buf[c^1])    // hoisted ptr + kt*64
//     s_waitcnt vmcnt(4)
//     s_barrier                  // #2: every wave's tile-j stage landed
//     straight-line body: 24 ds_read_b128 + 64 MFMA + stageB(j+1)
// ------------------------------------------------------------------
struct P8 { int wm, wn, l4, l15, l; };

__device__ __forceinline__ const bf16x8* ldsAddr(const bf16_t* buf, int row, int g) {
    return (const bf16x8*)(buf + row * 64 + ((g ^ (row & 7)) << 3));
}

__global__ __launch_bounds__(512, 2) void gemm8_kernel(
    const bf16_t* __restrict__ xb, const bf16_t* __restrict__ Wb,
    const float* __restrict__ bias,
    const bf16_t* __restrict__ tpad, const bf16_t* __restrict__ Btp,
    float* __restrict__ out) {
    __shared__ __align__(16) bf16_t lds[2][2][256 * 64];   // 128 KiB

    int tid = threadIdx.x;
    int w = tid >> 6, l = tid & 63;
    P8 p{w >> 2, w & 3, l >> 4, l & 15, l};

    // XCD-bijective swizzle: nwg = 1024, 8 XCDs, 128 per XCD
    int orig = blockIdx.x;
    int id = (orig & 7) * 128 + (orig >> 3);
    int mb = id >> 4, nb = id & 15;
    int row0 = mb * 256, col0 = nb * 256;
    int b = row0 >> 11;

    f32x4 acc[8][4] = {};

    // ---- hoisted per-thread stage addresses (computed once) ----
    const bf16_t* aSrcP[4];
    const bf16_t* bSrcP[4];
    int dstOff[4];
#pragma unroll
    for (int g = 0; g < 4; ++g) {
        int row = w * 32 + g * 8 + (l >> 3);
        int sc = (l & 7) ^ (row & 7);
        aSrcP[g] = xb + (size_t)(row0 + row) * DIN + sc * 8;
        bSrcP[g] = Wb + (size_t)(col0 + row) * DIN + sc * 8;
        dstOff[g] = (w * 32 + g * 8) * 64 + l * 8;
    }

    auto stageA = [&](int kt, int c) {
        int k0 = kt * 64;
#pragma unroll
        for (int g = 0; g < 4; ++g)
            __builtin_amdgcn_global_load_lds(GLP(aSrcP[g] + k0),
                                             LDSP(&lds[c][0][dstOff[g]]), 16, 0, 0);
    };
    auto stageB = [&](int kt, int c) {
        int k0 = kt * 64;
#pragma unroll
        for (int g = 0; g < 4; ++g)
            __builtin_amdgcn_global_load_lds(GLP(bSrcP[g] + k0),
                                             LDSP(&lds[c][1][dstOff[g]]), 16, 0, 0);
    };
    auto stageAdp = [&]() {
#pragma unroll
        for (int g = 0; g < 2; ++g) {
            int flat = g * 512 + tid;
            int row = flat >> 2, ch = flat & 3;
            __builtin_amdgcn_global_load_lds(
                GLP(tpad + (size_t)(row0 + row) * 32 + ch * 8),
                LDSP(&lds[0][0][flat * 8]), 16, 0, 0);
        }
#pragma unroll
        for (int g = 0; g < 2; ++g) {
            int flat = g * 512 + tid;
            int row = flat >> 2, ch = flat & 3;
            __builtin_amdgcn_global_load_lds(
                GLP(Btp + ((size_t)b * DOUT + col0 + row) * 32 + ch * 8),
                LDSP(&lds[0][1][flat * 8]), 16, 0, 0);
        }
    };

    auto loadA = [&](const bf16_t* bufA, int MH, bf16x8 (&ar)[4][2]) {
#pragma unroll
        for (int i = 0; i < 4; ++i) {
            int row = p.wm * 128 + MH * 64 + i * 16 + p.l15;
#pragma unroll
            for (int s = 0; s < 2; ++s)
                ar[i][s] = *ldsAddr(bufA, row, s * 4 + p.l4);
        }
    };
    auto loadB = [&](const bf16_t* bufB, int NH, bf16x8 (&br)[2][2]) {
#pragma unroll
        for (int jj = 0; jj < 2; ++jj) {
            int row = p.wn * 64 + NH * 32 + jj * 16 + p.l15;
#pragma unroll
            for (int s = 0; s < 2; ++s)
                br[jj][s] = *ldsAddr(bufB, row, s * 4 + p.l4);
        }
    };

    // prologue: stage ktile 0 -> buf0 (8 loads in flight)
    stageA(0, 0);
    stageB(0, 0);

#pragma unroll 1
    for (int j = 0; j < 64; ++j) {
        int c = j & 1;
        // barrier #1: all waves have finished reading buf[c^1] (iter j-1 body)
        __builtin_amdgcn_sched_barrier(0);
        __builtin_amdgcn_s_barrier();
        __builtin_amdgcn_sched_barrier(0);
        // now safe to write buf[c^1]
        if (j < 63) stageA(j + 1, c ^ 1);
        else        stageAdp();
        // wait for THIS tile's 8 loads (oldest) — the 4 new stay in flight
        asm volatile("s_waitcnt vmcnt(4)" ::: "memory");
        __builtin_amdgcn_sched_barrier(0);
        // barrier #2: every wave's tile-j stage has landed
        __builtin_amdgcn_s_barrier();
        __builtin_amdgcn_sched_barrier(0);

        const bf16_t* bufA = &lds[c][0][0];
        const bf16_t* bufB = &lds[c][1][0];

        bf16x8 a0[4][2], a1[4][2], b0[2][2], b1[2][2];
        loadA(bufA, 0, a0);
        loadB(bufB, 0, b0);
        if (j < 63) stageB(j + 1, c ^ 1);

        // quadrant (0,0)
#pragma unroll
        for (int s = 0; s < 2; ++s)
#pragma unroll
            for (int i = 0; i < 4; ++i)
#pragma unroll
                for (int jj = 0; jj < 2; ++jj)
                    acc[i][jj] = __builtin_amdgcn_mfma_f32_16x16x32_bf16(
                        a0[i][s], b0[jj][s], acc[i][jj], 0, 0, 0);
        loadB(bufB, 1, b1);
        // quadrant (0,1)
#pragma unroll
        for (int s = 0; s < 2; ++s)
#pragma unroll
            for (int i = 0; i < 4; ++i)
#pragma unroll
                for (int jj = 0; jj < 2; ++jj)
                    acc[i][2 + jj] = __builtin_amdgcn_mfma_f32_16x16x32_bf16(
                        a0[i][s], b1[jj][s], acc[i][2 + jj], 0, 0, 0);
        loadA(bufA, 1, a1);
        // quadrant (1,1)
#pragma unroll
        for (int s = 0; s < 2; ++s)
#pragma unroll
            for (int i = 0; i < 4; ++i)
#pragma unroll
                for (int jj = 0; jj < 2; ++jj)
                    acc[4 + i][2 + jj] = __builtin_amdgcn_mfma_f32_16x16x32_bf16(
                        a1[i][s], b1[jj][s], acc[4 + i][2 + jj], 0, 0, 0);
        // quadrant (1,0) — b0 still live, no reload
#pragma unroll
        for (int s = 0; s < 2; ++s)
#pragma unroll
            for (int i = 0; i < 4; ++i)
#pragma unroll
                for (int jj = 0; jj < 2; ++jj)
                    acc[4 + i][jj] = __builtin_amdgcn_mfma_f32_16x16x32_bf16(
                        a1[i][s], b0[jj][s], acc[4 + i][jj], 0, 0, 0);
    }

    // drain adapter loads, sync, then the K=32 adapter MFMA step (buf0, linear)
    asm volatile("s_waitcnt vmcnt(0)" ::: "memory");
    __builtin_amdgcn_sched_barrier(0);
    __builtin_amdgcn_s_barrier();
    __builtin_amdgcn_sched_barrier(0);
    {
        const bf16_t* A0 = &lds[0][0][0];
        const bf16_t* B0 = &lds[0][1][0];
        bf16x8 aa[8]; bf16x8 bb[4];
#pragma unroll
        for (int i = 0; i < 8; ++i)
            aa[i] = *(const bf16x8*)(A0 + (p.wm * 128 + i * 16 + p.l15) * 32 + p.l4 * 8);
#pragma unroll
        for (int j = 0; j < 4; ++j)
            bb[j] = *(const bf16x8*)(B0 + (p.wn * 64 + j * 16 + p.l15) * 32 + p.l4 * 8);
#pragma unroll
        for (int i = 0; i < 8; ++i)
#pragma unroll
            for (int j = 0; j < 4; ++j)
                acc[i][j] = __builtin_amdgcn_mfma_f32_16x16x32_bf16(aa[i], bb[j], acc[i][j], 0, 0, 0);
    }

    // ---- epilogue: + bias, store f32 ----
#pragma unroll
    for (int i = 0; i < 8; ++i) {
        int gm = row0 + p.wm * 128 + i * 16 + p.l4 * 4;
#pragma unroll
        for (int j = 0; j < 4; ++j) {
            int gn = col0 + p.wn * 64 + j * 16 + p.l15;
            float bsv = bias[gn];
#pragma unroll
            for (int q = 0; q < 4; ++q)
                out[(size_t)(gm + q) * DOUT + gn] = acc[i][j][q] + bsv;
        }
    }
}

// ------------------------------------------------------------------
// Fallback GEMM (m97 structure) for small-workspace paths
// ------------------------------------------------------------------
template<bool WPRE>
__global__ __launch_bounds__(256) void gemm_kernel(
    const float* __restrict__ xf,
    const float* __restrict__ Wf, const bf16_t* __restrict__ Wb,
    const float* __restrict__ bias,
    const bf16_t* __restrict__ tpad, const bf16_t* __restrict__ Btp,
    float* __restrict__ out) {
    __shared__ __align__(16) bf16_t As[128 * 64];
    __shared__ __align__(16) bf16_t Bs[128 * 64];

    int orig = blockIdx.x;
    int id = (orig & 7) * 512 + (orig >> 3);
    int mb = id >> 5, nb = id & 31;
    int row0 = mb * 128, col0 = nb * 128;
    int b = row0 >> 11;

    int tid = threadIdx.x;
    int w = tid >> 6, l = tid & 63;
    int wm = w >> 1, wn = w & 1;

    f32x4 acc[4][4] = {};

    for (int k0 = 0; k0 < DIN; k0 += 64) {
#pragma unroll
        for (int i = 0; i < 4; ++i) {
            int flat = i * 256 + tid;
            int row = flat >> 3, c8 = flat & 7;
            const float* src = xf + (size_t)(row0 + row) * DIN + k0 + c8 * 8;
            float4 v0 = *(const float4*)src;
            float4 v1 = *(const float4*)(src + 4);
            *(bf16x8*)(&As[flat * 8]) = cvt8(v0, v1);
        }
        if constexpr (WPRE) {
#pragma unroll
            for (int i = 0; i < 4; ++i) {
                int flat = i * 256 + tid;
                int row = flat >> 3, c8 = flat & 7;
                __builtin_amdgcn_global_load_lds(
                    GLP(Wb + (size_t)(col0 + row) * DIN + k0 + c8 * 8),
                    LDSP(&Bs[flat * 8]), 16, 0, 0);
            }
        } else {
#pragma unroll
            for (int i = 0; i < 4; ++i) {
                int flat = i * 256 + tid;
                int row = flat >> 3, c8 = flat & 7;
                const float* src = Wf + (size_t)(col0 + row) * DIN + k0 + c8 * 8;
                float4 v0 = *(const float4*)src;
                float4 v1 = *(const float4*)(src + 4);
                *(bf16x8*)(&Bs[flat * 8]) = cvt8(v0, v1);
            }
        }
        __syncthreads();
#pragma unroll
        for (int s = 0; s < 2; ++s) {
            int kr = s * 32 + (l >> 4) * 8;
            bf16x8 a[4], bf[4];
#pragma unroll
            for (int i = 0; i < 4; ++i)
                a[i] = *(const bf16x8*)(&As[(wm * 64 + i * 16 + (l & 15)) * 64 + kr]);
#pragma unroll
            for (int j = 0; j < 4; ++j)
                bf[j] = *(const bf16x8*)(&Bs[(wn * 64 + j * 16 + (l & 15)) * 64 + kr]);
#pragma unroll
            for (int i = 0; i < 4; ++i)
#pragma unroll
                for (int j = 0; j < 4; ++j)
                    acc[i][j] = __builtin_amdgcn_mfma_f32_16x16x32_bf16(a[i], bf[j], acc[i][j], 0, 0, 0);
        }
        __syncthreads();
    }

    {
#pragma unroll
        for (int i = 0; i < 2; ++i) {
            int flat = i * 256 + tid;
            int row = flat >> 2, c8 = flat & 3;
            __builtin_amdgcn_global_load_lds(
                GLP(tpad + (size_t)(row0 + row) * 32 + c8 * 8),
                LDSP(&As[flat * 8]), 16, 0, 0);
            __builtin_amdgcn_global_load_lds(
                GLP(Btp + ((size_t)b * DOUT + col0 + row) * 32 + c8 * 8),
                LDSP(&Bs[flat * 8]), 16, 0, 0);
        }
        __syncthreads();
        int kr = (l >> 4) * 8;
        bf16x8 a[4], bf[4];
#pragma unroll
        for (int i = 0; i < 4; ++i)
            a[i] = *(const bf16x8*)(&As[(wm * 64 + i * 16 + (l & 15)) * 32 + kr]);
#pragma unroll
        for (int j = 0; j < 4; ++j)
            bf[j] = *(const bf16x8*)(&Bs[(wn * 64 + j * 16 + (l & 15)) * 32 + kr]);
#pragma unroll
        for (int i = 0; i < 4; ++i)
#pragma unroll
            for (int j = 0; j < 4; ++j)
                acc[i][j] = __builtin_amdgcn_mfma_f32_16x16x32_bf16(a[i], bf[j], acc[i][j], 0, 0, 0);
    }

#pragma unroll
    for (int i = 0; i < 4; ++i) {
        int gm = row0 + wm * 64 + i * 16 + (l >> 4) * 4;
#pragma unroll
        for (int j = 0; j < 4; ++j) {
            int gn = col0 + wn * 64 + j * 16 + (l & 15);
            float bs = bias[gn];
#pragma unroll
            for (int q = 0; q < 4; ++q)
                out[(size_t)(gm + q) * DOUT + gn] = acc[i][j][q] + bs;
        }
    }
}

// ------------------------------------------------------------------
extern "C" void kernel_launch(void* const* d_in, const int* in_sizes, int n_in,
                              void* d_out, int out_size, void* d_ws, size_t ws_size,
                              hipStream_t stream) {
    const float* x        = (const float*)d_in[0];
    const int*   task_ids = (const int*)d_in[1];
    const float* W        = (const float*)d_in[2];
    const float* bias     = (const float*)d_in[3];
    const float* logits   = (const float*)d_in[4];
    const float* lora_a   = (const float*)d_in[5];
    const float* lora_b   = (const float*)d_in[6];
    float* out = (float*)d_out;

    char* ws = (char*)d_ws;
    size_t off = 0;
    auto alloc = [&](size_t bytes) {
        char* p = ws + off;
        off += (bytes + 255) & ~(size_t)255;
        return p;
    };
    bf16_t* Abt  = (bf16_t*)alloc((size_t)BS * RANK * DIN * 2);
    bf16_t* Btp  = (bf16_t*)alloc((size_t)BS * DOUT * 32 * 2);
    bf16_t* tpad = (bf16_t*)alloc((size_t)MTOT * 32 * 2);
    bf16_t* Wb   = (bf16_t*)alloc((size_t)DOUT * DIN * 2);
    size_t w_end = off;
    bf16_t* xb   = (bf16_t*)alloc((size_t)MTOT * DIN * 2);
    size_t full_end = off;

    bool wpre = ws_size >= w_end;
    bool xpre = ws_size >= full_end;

    mix_kernel<<<dim3(64, 8), 256, 0, stream>>>(logits, task_ids, lora_a, lora_b, Abt, Btp);
    if (wpre)
        convw_kernel<<<(DOUT * DIN / 8) / 256, 256, 0, stream>>>(W, Wb);
    if (xpre)
        tconv_kernel<true><<<MTOT / 64, 256, 0, stream>>>(x, Abt, xb, tpad);
    else
        tconv_kernel<false><<<MTOT / 64, 256, 0, stream>>>(x, Abt, nullptr, tpad);

    if (xpre) {
        int nblk = (MTOT / 256) * (DOUT / 256);   // 1024
        gemm8_kernel<<<nblk, 512, 0, stream>>>(xb, Wb, bias, tpad, Btp, out);
    } else {
        int nblk = (MTOT / 128) * (DOUT / 128);   // 4096
        if (wpre)
            gemm_kernel<true><<<nblk, 256, 0, stream>>>(x, W, Wb, bias, tpad, Btp, out);
        else
            gemm_kernel<false><<<nblk, 256, 0, stream>>>(x, W, Wb, bias, tpad, Btp, out);
    }
}